// Round 7
// baseline (724.400 us; speedup 1.0000x reference)
//
#include <hip/hip_runtime.h>

typedef _Float16 f16x8 __attribute__((ext_vector_type(8)));
typedef float f32x4 __attribute__((ext_vector_type(4)));
typedef unsigned short us4v __attribute__((ext_vector_type(4)));

// Padded row pitches (halves). Pad = +32 halves (64B) breaks power-of-2 HBM
// channel camping; pitch*2 is 16B-aligned so f16x8 loads stay aligned.
#define PITCH_W  6176
#define PITCH_P  8224
#define PITCH_WL 12320
#define PITCH_PT 4128

__device__ inline unsigned short f16b(float v) {
    _Float16 h = (_Float16)v;
    return __builtin_bit_cast(unsigned short, h);
}

__device__ inline void atomAddF(float* p, float v) {
    __hip_atomic_fetch_add(p, v, __ATOMIC_RELAXED, __HIP_MEMORY_SCOPE_AGENT);
}

// ---------------- one-time conversion fp32 -> fp16 with pitched rows ----------------
// float4 units: W 3145728 (1536/row), P 4194304 (2048/row), WL 12582912 (3072/row)
__global__ __launch_bounds__(256) void cvt_all(const float* __restrict__ W, const float* __restrict__ P,
                                               const float* __restrict__ WL,
                                               unsigned short* __restrict__ Wb, unsigned short* __restrict__ Pb,
                                               unsigned short* __restrict__ WLb) {
    int i = blockIdx.x * 256 + threadIdx.x;
    const float* src; unsigned short* dst; int idx; size_t o4;
    if (i < 3145728) {
        src = W; dst = Wb; idx = i;
        int r = idx / 1536, c = idx - r * 1536;
        o4 = (size_t)r * (PITCH_W / 4) + c;
    } else if (i < 3145728 + 4194304) {
        src = P; dst = Pb; idx = i - 3145728;
        int r = idx / 2048, c = idx - r * 2048;
        o4 = (size_t)r * (PITCH_P / 4) + c;
    } else {
        src = WL; dst = WLb; idx = i - (3145728 + 4194304);
        int r = idx / 3072, c = idx - r * 3072;
        o4 = (size_t)r * (PITCH_WL / 4) + c;
    }
    float4 v = ((const float4*)src)[idx];
    us4v o;
    o[0] = f16b(v.x); o[1] = f16b(v.y); o[2] = f16b(v.z); o[3] = f16b(v.w);
    ((us4v*)dst)[o4] = o;
}

// P [2048][4096][2] f32  ->  PT [4096][PITCH_PT] f16 where PT[m][n*2+p] = P[n][m][p]
__global__ __launch_bounds__(256) void transpose_p(const float* __restrict__ P,
                                                   unsigned short* __restrict__ PT) {
    __shared__ unsigned int lds[64][33];
    int bid = blockIdx.x;
    int m0 = (bid & 127) * 32;
    int n0 = (bid >> 7) * 64;
    int tid = threadIdx.x;
    const float2* P2 = (const float2*)P;
    #pragma unroll
    for (int it = 0; it < 8; ++it) {
        int idx = it * 256 + tid;
        int nl = idx >> 5, ml = idx & 31;
        float2 v = P2[(size_t)(n0 + nl) * 4096 + (m0 + ml)];
        unsigned int pk = (unsigned int)f16b(v.x) | ((unsigned int)f16b(v.y) << 16);
        lds[nl][ml] = pk;
    }
    __syncthreads();
    unsigned int* PTu = (unsigned int*)PT;
    #pragma unroll
    for (int it = 0; it < 8; ++it) {
        int idx = it * 256 + tid;
        int ml = idx >> 6, nl = idx & 63;
        PTu[(size_t)(m0 + ml) * (PITCH_PT / 2) + (n0 + nl)] = lds[nl][ml];
    }
}

// ---------------- per-layer B-matrix build, BN fused (fragment layout) ----------------
// Fragment layout: elem index ((t*2+h)*64+lane)*8+e holds B[k=t*32+(lane>>4)*8+e][g=h*16+(lane&15)]
__global__ __launch_bounds__(256) void build_b(
    const float* __restrict__ srcx, const float* __restrict__ srcy,
    int Fin, int Fout, int buildB2, int use_bn,
    const float* __restrict__ stats,
    const float* __restrict__ gx, const float* __restrict__ btx,
    const float* __restrict__ gy, const float* __restrict__ bty,
    const float* __restrict__ w1a, const float* __restrict__ w1b,
    const float* __restrict__ w2a, const float* __restrict__ w2b,
    unsigned short* __restrict__ B1f, unsigned short* __restrict__ B2f) {
    int tid0 = blockIdx.x * 256 + threadIdx.x;
    const int NB1 = 14336 * 32;
    int isB2 = 0, t2 = tid0;
    if (tid0 >= NB1) {
        if (!buildB2) return;
        isB2 = 1; t2 = tid0 - NB1;
        if (t2 >= 16384 * 32) return;
    }
    int e = t2 & 7, lane = (t2 >> 3) & 63, hh = (t2 >> 9) & 1, t = t2 >> 10;
    int k = (t << 5) | ((lane >> 4) << 3) | e;
    int g = (hh << 4) | (lane & 15);
    float v = 0.f;
    if (g < Fout) {
        const float* hr; const float* wc; int useY;
        if (!isB2) {
            if (k < 6144) { int m = k / 3, j = k - 3 * m; hr = srcx + m * Fin; wc = w1a + (j * Fin) * Fout + g; useY = 0; }
            else { int k2 = k - 6144; int m = k2 >> 1, p = k2 & 1; hr = srcy + m * Fin; wc = w1b + (p * Fin) * Fout + g; useY = 1; }
        } else {
            if (k < 12288) { int m = k / 3, j = k - 3 * m; hr = srcy + m * Fin; wc = w2a + (j * Fin) * Fout + g; useY = 1; }
            else { int k2 = k - 12288; int n = k2 >> 1, p = k2 & 1; hr = srcx + n * Fin; wc = w2b + (p * Fin) * Fout + g; useY = 0; }
        }
        float a = 0.f;
        if (use_bn) {
            const float* st = useY ? stats + 64 : stats;
            const float* gv = useY ? gy : gx;
            const float* bv = useY ? bty : btx;
            float invn = useY ? (1.f / 4096.f) : (1.f / 2048.f);
            #pragma unroll
            for (int f = 0; f < 32; ++f) {
                float mean = st[f] * invn;
                float var = st[32 + f] * invn - mean * mean;
                float sc = gv[f] * rsqrtf(var + 1e-5f);
                float h = sc * (hr[f] - mean) + bv[f];
                a += h * wc[f * Fout];
            }
        } else {
            for (int f = 0; f < Fin; ++f) a += hr[f] * wc[f * Fout];
        }
        v = a;
    }
    if (!isB2) B1f[t2] = f16b(v); else B2f[t2] = f16b(v);
}

// ---------------- split-K MFMA GEMM, 4-wave k-split per tile ----------------
// Tile = 32 rows x 1024 K per WG; wave w owns k-quarter [kb+256w, kb+256w+256).
// x-branch: 64 mwgs x 14 ksegs = 896 WGs (segs 0..5 = W, 6..13 = P)
// y-branch: 128 mwgs x 16 ksegs = 2048 WGs (segs 0..11 = WL, 12..15 = PT)
__global__ __launch_bounds__(256) void gemm_k(
    const unsigned short* __restrict__ Wb, const unsigned short* __restrict__ Pb,
    const unsigned short* __restrict__ WLb, const unsigned short* __restrict__ PTb,
    const unsigned short* __restrict__ B1f, const unsigned short* __restrict__ B2f,
    float* __restrict__ px, float* __restrict__ py, float* __restrict__ stats, int nwgx) {
    __shared__ float lds[4][1024];
    int bid = blockIdx.x;
    if (bid == 0 && threadIdx.x < 128) stats[threadIdx.x] = 0.f;  // pre-zero for next reduce
    const unsigned short* Bf;
    float* Z;
    int seg, Mbase, pitch, kloc, kb;
    const unsigned short* A16;
    if (bid < nwgx) {
        Bf = B1f;
        int mwg = bid / 14; seg = bid % 14;
        Mbase = mwg * 32;
        kb = seg << 10;
        Z = px + (size_t)seg * 65536;
        if (seg < 6) { pitch = PITCH_W; kloc = kb;        A16 = Wb; }
        else         { pitch = PITCH_P; kloc = kb - 6144; A16 = Pb; }
    } else {
        int b2 = bid - nwgx;
        Bf = B2f;
        int mwg = b2 / 16; seg = b2 % 16;
        Mbase = mwg * 32;
        kb = seg << 10;
        Z = py + (size_t)seg * 131072;
        if (seg < 12) { pitch = PITCH_WL; kloc = kb;         A16 = WLb; }
        else          { pitch = PITCH_PT; kloc = kb - 12288; A16 = PTb; }
    }
    int wid = threadIdx.x >> 6, lane = threadIdx.x & 63;
    int kq = wid << 8;  // this wave's 256-K quarter offset
    const unsigned short* ap0 = A16 + (size_t)(Mbase + (lane & 15)) * pitch + kloc + kq + ((lane >> 4) << 3);
    const unsigned short* ap1 = ap0 + (size_t)16 * pitch;
    const unsigned short* bp = Bf + ((size_t)((kb + kq) >> 5)) * 1024 + lane * 8;
    f32x4 acc00 = {0.f,0.f,0.f,0.f}, acc01 = {0.f,0.f,0.f,0.f};
    f32x4 acc10 = {0.f,0.f,0.f,0.f}, acc11 = {0.f,0.f,0.f,0.f};
    #pragma unroll
    for (int ks = 0; ks < 8; ++ks) {
        f16x8 a0 = *(const f16x8*)ap0;
        f16x8 a1 = *(const f16x8*)ap1;
        f16x8 b0 = *(const f16x8*)bp;
        f16x8 b1 = *(const f16x8*)(bp + 512);
        acc00 = __builtin_amdgcn_mfma_f32_16x16x32_f16(a0, b0, acc00, 0, 0, 0);
        acc10 = __builtin_amdgcn_mfma_f32_16x16x32_f16(a1, b0, acc10, 0, 0, 0);
        acc01 = __builtin_amdgcn_mfma_f32_16x16x32_f16(a0, b1, acc01, 0, 0, 0);
        acc11 = __builtin_amdgcn_mfma_f32_16x16x32_f16(a1, b1, acc11, 0, 0, 0);
        ap0 += 32; ap1 += 32; bp += 1024;
    }
    // stash quarter-accumulators: tile index = row*32 + col
    int col = lane & 15, r0 = (lane >> 4) << 2;
    float* l = lds[wid];
    #pragma unroll
    for (int r = 0; r < 4; ++r) {
        l[(r0 + r) * 32 + col]            = acc00[r];
        l[(r0 + r) * 32 + col + 16]       = acc01[r];
        l[(r0 + r + 16) * 32 + col]       = acc10[r];
        l[(r0 + r + 16) * 32 + col + 16]  = acc11[r];
    }
    __syncthreads();
    // 256 threads sum the 4 quarters, write one float4 each (coalesced 4 KB tile)
    int t = threadIdx.x;
    float4 a = ((const float4*)lds[0])[t];
    float4 b = ((const float4*)lds[1])[t];
    float4 c = ((const float4*)lds[2])[t];
    float4 d = ((const float4*)lds[3])[t];
    float4 s;
    s.x = (a.x + b.x) + (c.x + d.x);
    s.y = (a.y + b.y) + (c.y + d.y);
    s.z = (a.z + b.z) + (c.z + d.z);
    s.w = (a.w + b.w) + (c.w + d.w);
    ((float4*)(Z + (size_t)Mbase * 32))[t] = s;
}

// ---------------- reduce partials + bias + relu-half + column stats ----------------
// blocks 0..63: x (65536 elems), 64..191: y (131072 elems); each thread one float4
__global__ __launch_bounds__(256) void reduce_stats(
    const float* __restrict__ px, const float* __restrict__ py,
    const float* __restrict__ bx, const float* __restrict__ by,
    float* __restrict__ zax, float* __restrict__ zay,
    float* __restrict__ stats) {
    __shared__ float lsum[4][8][8];
    int bid = blockIdx.x, tid = threadIdx.x;
    const float4* src; const float* bias; float4* dst; float* st; int nseg, i4, stride4;
    if (bid < 64) { src = (const float4*)px; bias = bx; dst = (float4*)zax; st = stats;      nseg = 14; i4 = bid * 256 + tid;        stride4 = 16384; }
    else          { src = (const float4*)py; bias = by; dst = (float4*)zay; st = stats + 64; nseg = 16; i4 = (bid - 64) * 256 + tid; stride4 = 32768; }
    float4 s = {0.f, 0.f, 0.f, 0.f};
    for (int g = 0; g < nseg; ++g) {
        float4 v = src[(size_t)g * stride4 + i4];
        s.x += v.x; s.y += v.y; s.z += v.z; s.w += v.w;
    }
    int c0 = (i4 & 7) * 4;
    float4 b4 = *(const float4*)(bias + c0);
    s.x += b4.x; s.y += b4.y; s.z += b4.z; s.w += b4.w;
    if (c0 < 16) {
        s.x = fmaxf(s.x, 0.f); s.y = fmaxf(s.y, 0.f);
        s.z = fmaxf(s.z, 0.f); s.w = fmaxf(s.w, 0.f);
    }
    dst[i4] = s;
    float4 s2 = {s.x * s.x, s.y * s.y, s.z * s.z, s.w * s.w};
    #pragma unroll
    for (int mask = 8; mask <= 32; mask <<= 1) {
        s.x += __shfl_xor(s.x, mask); s.y += __shfl_xor(s.y, mask);
        s.z += __shfl_xor(s.z, mask); s.w += __shfl_xor(s.w, mask);
        s2.x += __shfl_xor(s2.x, mask); s2.y += __shfl_xor(s2.y, mask);
        s2.z += __shfl_xor(s2.z, mask); s2.w += __shfl_xor(s2.w, mask);
    }
    int w = tid >> 6, ln = tid & 63;
    if (ln < 8) {
        lsum[w][ln][0] = s.x;  lsum[w][ln][1] = s.y;  lsum[w][ln][2] = s.z;  lsum[w][ln][3] = s.w;
        lsum[w][ln][4] = s2.x; lsum[w][ln][5] = s2.y; lsum[w][ln][6] = s2.z; lsum[w][ln][7] = s2.w;
    }
    __syncthreads();
    if (tid < 64) {
        int q = tid >> 3, e = tid & 7;
        float v = lsum[0][q][e] + lsum[1][q][e] + lsum[2][q][e] + lsum[3][q][e];
        int col = q * 4 + (e & 3);
        atomAddF((e < 4) ? &st[col] : &st[32 + col], v);
    }
}

// ---------------- final: sum x-partials + bl -> out ----------------
__global__ __launch_bounds__(256) void out_final(const float* __restrict__ px,
                                                 const float* __restrict__ bl,
                                                 float* __restrict__ out) {
    int tid = blockIdx.x * 256 + threadIdx.x;
    if (tid < 4096) {
        int n = tid >> 1, c = tid & 1;
        float a = bl[c];
        for (int s = 0; s < 14; ++s) a += px[(size_t)s * 65536 + n * 32 + c];
        out[tid] = a;
    }
}

extern "C" void kernel_launch(void* const* d_in, const int* in_sizes, int n_in,
                              void* d_out, int out_size, void* d_ws, size_t ws_size,
                              hipStream_t stream) {
    const float* W    = (const float*)d_in[0];
    const float* x    = (const float*)d_in[1];
    const float* WL   = (const float*)d_in[2];
    const float* y    = (const float*)d_in[3];
    const float* P    = (const float*)d_in[4];
    const float* wx2x0 = (const float*)d_in[5];
    const float* wy2x0 = (const float*)d_in[6];
    const float* bx0   = (const float*)d_in[7];
    const float* wy2y0 = (const float*)d_in[8];
    const float* wx2y0 = (const float*)d_in[9];
    const float* by0   = (const float*)d_in[10];
    const float* gx0   = (const float*)d_in[11];
    const float* btx0  = (const float*)d_in[12];
    const float* gy0   = (const float*)d_in[13];
    const float* bty0  = (const float*)d_in[14];
    const float* wx2x_m = (const float*)d_in[15];
    const float* wy2x_m = (const float*)d_in[16];
    const float* bx_m   = (const float*)d_in[17];
    const float* wy2y_m = (const float*)d_in[18];
    const float* wx2y_m = (const float*)d_in[19];
    const float* by_m   = (const float*)d_in[20];
    const float* gx_m   = (const float*)d_in[21];
    const float* btx_m  = (const float*)d_in[22];
    const float* gy_m   = (const float*)d_in[23];
    const float* bty_m  = (const float*)d_in[24];
    const float* wlx = (const float*)d_in[25];
    const float* wly = (const float*)d_in[26];
    const float* bl  = (const float*)d_in[27];

    char* base = (char*)d_ws;
    unsigned short* Wb  = (unsigned short*)(base + 0);          // 2048*6176*2  = 25,296,896
    unsigned short* Pb  = (unsigned short*)(base + 25296896);   // 2048*8224*2  = 33,685,504
    unsigned short* WLb = (unsigned short*)(base + 58982400);   // 4096*12320*2 = 100,925,440
    unsigned short* PTb = (unsigned short*)(base + 159907840);  // 4096*4128*2  = 33,816,576
    unsigned short* B1f = (unsigned short*)(base + 193724416);  // 917,504
    unsigned short* B2f = (unsigned short*)(base + 194641920);  // 1,048,576
    float* zax   = (float*)(base + 195690496);  // 262,144
    float* zay   = (float*)(base + 195952640);  // 524,288
    float* stats = (float*)(base + 196476928);  // 512
    float* px    = (float*)(base + 196477440);  // 14*65536*4  = 3,670,016
    float* py    = (float*)(base + 200147456);  // 16*131072*4 = 8,388,608 -> ends 208,536,064

    // one-time conversions (pitched)
    cvt_all<<<77824, 256, 0, stream>>>(W, P, WL, Wb, Pb, WLb);
    transpose_p<<<4096, 256, 0, stream>>>(P, PTb);

    // block 0 (Fin = 1, raw x/y, no bn)
    build_b<<<3840, 256, 0, stream>>>(x, y, 1, 32, 1, 0, nullptr, nullptr, nullptr, nullptr, nullptr,
                                      wx2x0, wy2x0, wy2y0, wx2y0, B1f, B2f);
    gemm_k<<<2944, 256, 0, stream>>>(Wb, Pb, WLb, PTb, B1f, B2f, px, py, stats, 896);
    reduce_stats<<<192, 256, 0, stream>>>(px, py, bx0, by0, zax, zay, stats);

    // blocks 1..6 (middle weights i = 0..5); bn params of block i come from previous block
    for (int i = 0; i < 6; ++i) {
        const float* gv  = (i == 0) ? gx0  : gx_m  + (i - 1) * 32;
        const float* bv  = (i == 0) ? btx0 : btx_m + (i - 1) * 32;
        const float* gvy = (i == 0) ? gy0  : gy_m  + (i - 1) * 32;
        const float* bvy = (i == 0) ? bty0 : bty_m + (i - 1) * 32;
        build_b<<<3840, 256, 0, stream>>>(zax, zay, 32, 32, 1, 1, stats, gv, bv, gvy, bvy,
                                          wx2x_m + i * 3072, wy2x_m + i * 2048,
                                          wy2y_m + i * 3072, wx2y_m + i * 2048, B1f, B2f);
        gemm_k<<<2944, 256, 0, stream>>>(Wb, Pb, WLb, PTb, B1f, B2f, px, py, stats, 896);
        reduce_stats<<<192, 256, 0, stream>>>(px, py, bx_m + i * 32, by_m + i * 32, zax, zay, stats);
    }

    // final layer: bn of block 6 (gx_m[5]...), linear weights, x-branch only
    build_b<<<1792, 256, 0, stream>>>(zax, zay, 32, 2, 0, 1, stats,
                                      gx_m + 5 * 32, btx_m + 5 * 32, gy_m + 5 * 32, bty_m + 5 * 32,
                                      wlx, wly, nullptr, nullptr, B1f, B2f);
    gemm_k<<<896, 256, 0, stream>>>(Wb, Pb, WLb, PTb, B1f, B2f, px, py, stats, 896);
    out_final<<<16, 256, 0, stream>>>(px, bl, (float*)d_out);
}

// Round 8
// 683.125 us; speedup vs baseline: 1.0604x; 1.0604x over previous
//
#include <hip/hip_runtime.h>

typedef _Float16 f16x8 __attribute__((ext_vector_type(8)));
typedef float f32x4 __attribute__((ext_vector_type(4)));

// Packed ("fragment-major") A layout: half-index of element (row,k) in a matrix
// with row-length K (halves):
//   panel = row>>4, kstep = k>>5, g = (k>>3)&3, e = k&7
//   off = panel*(K*16) + kstep*512 + (g*16 + (row&15))*8 + e
// A wave reading lane*8 .. lane*8+7 at one kstep gets a contiguous 1KB block ==
// exactly its MFMA A-fragment (row = lane&15, k = kstep*32 + (lane>>4)*8 + e).

__device__ inline unsigned short f16b(float v) {
    _Float16 h = (_Float16)v;
    return __builtin_bit_cast(unsigned short, h);
}

__device__ inline void atomAddF(float* p, float v) {
    __hip_atomic_fetch_add(p, v, __ATOMIC_RELAXED, __HIP_MEMORY_SCOPE_AGENT);
}

// ---------------- one-time fp32 -> packed fp16 ----------------
template<int K>
__device__ inline void pack_cvt(const float* __restrict__ src, unsigned short* __restrict__ dst, int u) {
    // u = 16B-unit index in packed dst; this thread writes halves [u*8, u*8+8)
    int o = u * 8;
    int panel = o / (K * 16);
    int rem = o - panel * (K * 16);
    int kstep = rem >> 9;
    int rem2 = rem & 511;
    int g = rem2 >> 7;
    int r15 = (rem2 >> 3) & 15;
    int row = (panel << 4) | r15;
    int k = (kstep << 5) | (g << 3);
    const float4* s = (const float4*)(src + (size_t)row * K + k);
    float4 v0 = s[0], v1 = s[1];
    uint4 q;
    q.x = (unsigned)f16b(v0.x) | ((unsigned)f16b(v0.y) << 16);
    q.y = (unsigned)f16b(v0.z) | ((unsigned)f16b(v0.w) << 16);
    q.z = (unsigned)f16b(v1.x) | ((unsigned)f16b(v1.y) << 16);
    q.w = (unsigned)f16b(v1.z) | ((unsigned)f16b(v1.w) << 16);
    ((uint4*)dst)[u] = q;
}

// 16B-units: W 1572864, P 2097152, WL 6291456 -> 9961472 total = 38912 WGs
__global__ __launch_bounds__(256) void cvt_pack(const float* __restrict__ W, const float* __restrict__ P,
                                                const float* __restrict__ WL,
                                                unsigned short* __restrict__ Wb, unsigned short* __restrict__ Pb,
                                                unsigned short* __restrict__ WLb) {
    int u = blockIdx.x * 256 + threadIdx.x;
    if (u < 1572864) pack_cvt<6144>(W, Wb, u);
    else if (u < 1572864 + 2097152) pack_cvt<8192>(P, Pb, u - 1572864);
    else pack_cvt<12288>(WL, WLb, u - (1572864 + 2097152));
}

// P [2048][4096][2] f32 -> packed PT (rows m 0..4095, K=4096, PT[m][n*2+p] = P[n][m][p])
__global__ __launch_bounds__(256) void transpose_p(const float* __restrict__ P,
                                                   unsigned short* __restrict__ PT) {
    __shared__ unsigned int lds[64][33];
    int bid = blockIdx.x;
    int m0 = (bid & 127) * 32;
    int n0 = (bid >> 7) * 64;
    int tid = threadIdx.x;
    const float2* P2 = (const float2*)P;
    #pragma unroll
    for (int it = 0; it < 8; ++it) {
        int idx = it * 256 + tid;
        int nl = idx >> 5, ml = idx & 31;
        float2 v = P2[(size_t)(n0 + nl) * 4096 + (m0 + ml)];
        unsigned int pk = (unsigned int)f16b(v.x) | ((unsigned int)f16b(v.y) << 16);
        lds[nl][ml] = pk;
    }
    __syncthreads();
    unsigned int* PTu = (unsigned int*)PT;
    #pragma unroll
    for (int it = 0; it < 8; ++it) {
        int idx = it * 256 + tid;
        int ml = idx >> 6, nl = idx & 63;
        int row = m0 + ml;
        int k2 = (n0 + nl) * 2;
        int o = ((row >> 4) << 16) | ((k2 >> 5) << 9) | (((((k2 >> 3) & 3) << 4) | (row & 15)) << 3) | (k2 & 7);
        PTu[o >> 1] = lds[nl][ml];
    }
}

// ---------------- per-layer B-matrix build, BN fused (fragment layout) ----------------
__global__ __launch_bounds__(256) void build_b(
    const float* __restrict__ srcx, const float* __restrict__ srcy,
    int Fin, int Fout, int buildB2, int use_bn,
    const float* __restrict__ stats,
    const float* __restrict__ gx, const float* __restrict__ btx,
    const float* __restrict__ gy, const float* __restrict__ bty,
    const float* __restrict__ w1a, const float* __restrict__ w1b,
    const float* __restrict__ w2a, const float* __restrict__ w2b,
    unsigned short* __restrict__ B1f, unsigned short* __restrict__ B2f) {
    int tid0 = blockIdx.x * 256 + threadIdx.x;
    const int NB1 = 14336 * 32;
    int isB2 = 0, t2 = tid0;
    if (tid0 >= NB1) {
        if (!buildB2) return;
        isB2 = 1; t2 = tid0 - NB1;
        if (t2 >= 16384 * 32) return;
    }
    int e = t2 & 7, lane = (t2 >> 3) & 63, hh = (t2 >> 9) & 1, t = t2 >> 10;
    int k = (t << 5) | ((lane >> 4) << 3) | e;
    int g = (hh << 4) | (lane & 15);
    float v = 0.f;
    if (g < Fout) {
        const float* hr; const float* wc; int useY;
        if (!isB2) {
            if (k < 6144) { int m = k / 3, j = k - 3 * m; hr = srcx + m * Fin; wc = w1a + (j * Fin) * Fout + g; useY = 0; }
            else { int k2 = k - 6144; int m = k2 >> 1, p = k2 & 1; hr = srcy + m * Fin; wc = w1b + (p * Fin) * Fout + g; useY = 1; }
        } else {
            if (k < 12288) { int m = k / 3, j = k - 3 * m; hr = srcy + m * Fin; wc = w2a + (j * Fin) * Fout + g; useY = 1; }
            else { int k2 = k - 12288; int n = k2 >> 1, p = k2 & 1; hr = srcx + n * Fin; wc = w2b + (p * Fin) * Fout + g; useY = 0; }
        }
        float a = 0.f;
        if (use_bn) {
            const float* st = useY ? stats + 64 : stats;
            const float* gv = useY ? gy : gx;
            const float* bv = useY ? bty : btx;
            float invn = useY ? (1.f / 4096.f) : (1.f / 2048.f);
            #pragma unroll
            for (int f = 0; f < 32; ++f) {
                float mean = st[f] * invn;
                float var = st[32 + f] * invn - mean * mean;
                float sc = gv[f] * rsqrtf(var + 1e-5f);
                float h = sc * (hr[f] - mean) + bv[f];
                a += h * wc[f * Fout];
            }
        } else {
            for (int f = 0; f < Fin; ++f) a += hr[f] * wc[f * Fout];
        }
        v = a;
    }
    if (!isB2) B1f[t2] = f16b(v); else B2f[t2] = f16b(v);
}

// ---------------- split-K MFMA GEMM over packed A, 4-wave k-split per tile ----------------
// Tile = 32 rows x 1024 K per WG; wave w owns k-quarter. A-loads are 1KB contiguous.
// x-branch: 64 mwgs x 14 ksegs = 896 WGs (segs 0..5 = W, 6..13 = P)
// y-branch: 128 mwgs x 16 ksegs = 2048 WGs (segs 0..11 = WL, 12..15 = PT)
__global__ __launch_bounds__(256) void gemm_k(
    const unsigned short* __restrict__ Wb, const unsigned short* __restrict__ Pb,
    const unsigned short* __restrict__ WLb, const unsigned short* __restrict__ PTb,
    const unsigned short* __restrict__ B1f, const unsigned short* __restrict__ B2f,
    float* __restrict__ px, float* __restrict__ py, float* __restrict__ stats, int nwgx) {
    __shared__ float lds[4][1024];
    int bid = blockIdx.x;
    if (bid == 0 && threadIdx.x < 128) stats[threadIdx.x] = 0.f;  // pre-zero for next reduce
    const unsigned short* Bf;
    float* Z;
    int seg, Mbase, K, kloc, kb;
    const unsigned short* A16;
    if (bid < nwgx) {
        Bf = B1f;
        int mwg = bid / 14; seg = bid % 14;
        Mbase = mwg * 32;
        kb = seg << 10;
        Z = px + (size_t)seg * 65536;
        if (seg < 6) { K = 6144; kloc = kb;        A16 = Wb; }
        else         { K = 8192; kloc = kb - 6144; A16 = Pb; }
    } else {
        int b2 = bid - nwgx;
        Bf = B2f;
        int mwg = b2 / 16; seg = b2 % 16;
        Mbase = mwg * 32;
        kb = seg << 10;
        Z = py + (size_t)seg * 131072;
        if (seg < 12) { K = 12288; kloc = kb;         A16 = WLb; }
        else          { K = 4096;  kloc = kb - 12288; A16 = PTb; }
    }
    int wid = threadIdx.x >> 6, lane = threadIdx.x & 63;
    int kq = wid << 8;  // this wave's 256-K quarter
    const unsigned short* ap0 = A16 + (size_t)(Mbase >> 4) * (K * 16)
                              + (size_t)((kloc + kq) >> 5) * 512 + lane * 8;
    const unsigned short* ap1 = ap0 + (size_t)K * 16;  // next 16-row panel
    const unsigned short* bp = Bf + ((size_t)((kb + kq) >> 5)) * 1024 + lane * 8;
    f32x4 acc00 = {0.f,0.f,0.f,0.f}, acc01 = {0.f,0.f,0.f,0.f};
    f32x4 acc10 = {0.f,0.f,0.f,0.f}, acc11 = {0.f,0.f,0.f,0.f};
    #pragma unroll
    for (int ks = 0; ks < 8; ++ks) {
        f16x8 a0 = *(const f16x8*)ap0;
        f16x8 a1 = *(const f16x8*)ap1;
        f16x8 b0 = *(const f16x8*)bp;
        f16x8 b1 = *(const f16x8*)(bp + 512);
        acc00 = __builtin_amdgcn_mfma_f32_16x16x32_f16(a0, b0, acc00, 0, 0, 0);
        acc10 = __builtin_amdgcn_mfma_f32_16x16x32_f16(a1, b0, acc10, 0, 0, 0);
        acc01 = __builtin_amdgcn_mfma_f32_16x16x32_f16(a0, b1, acc01, 0, 0, 0);
        acc11 = __builtin_amdgcn_mfma_f32_16x16x32_f16(a1, b1, acc11, 0, 0, 0);
        ap0 += 512; ap1 += 512; bp += 1024;
    }
    // stash quarter-accumulators: tile index = row*32 + col
    int col = lane & 15, r0 = (lane >> 4) << 2;
    float* l = lds[wid];
    #pragma unroll
    for (int r = 0; r < 4; ++r) {
        l[(r0 + r) * 32 + col]            = acc00[r];
        l[(r0 + r) * 32 + col + 16]       = acc01[r];
        l[(r0 + r + 16) * 32 + col]       = acc10[r];
        l[(r0 + r + 16) * 32 + col + 16]  = acc11[r];
    }
    __syncthreads();
    // 256 threads sum the 4 quarters, write one float4 each (coalesced 4KB tile)
    int t = threadIdx.x;
    float4 a = ((const float4*)lds[0])[t];
    float4 b = ((const float4*)lds[1])[t];
    float4 c = ((const float4*)lds[2])[t];
    float4 d = ((const float4*)lds[3])[t];
    float4 s;
    s.x = (a.x + b.x) + (c.x + d.x);
    s.y = (a.y + b.y) + (c.y + d.y);
    s.z = (a.z + b.z) + (c.z + d.z);
    s.w = (a.w + b.w) + (c.w + d.w);
    ((float4*)(Z + (size_t)Mbase * 32))[t] = s;
}

// ---------------- reduce partials + bias + relu-half + column stats ----------------
__global__ __launch_bounds__(256) void reduce_stats(
    const float* __restrict__ px, const float* __restrict__ py,
    const float* __restrict__ bx, const float* __restrict__ by,
    float* __restrict__ zax, float* __restrict__ zay,
    float* __restrict__ stats) {
    __shared__ float lsum[4][8][8];
    int bid = blockIdx.x, tid = threadIdx.x;
    const float4* src; const float* bias; float4* dst; float* st; int nseg, i4, stride4;
    if (bid < 64) { src = (const float4*)px; bias = bx; dst = (float4*)zax; st = stats;      nseg = 14; i4 = bid * 256 + tid;        stride4 = 16384; }
    else          { src = (const float4*)py; bias = by; dst = (float4*)zay; st = stats + 64; nseg = 16; i4 = (bid - 64) * 256 + tid; stride4 = 32768; }
    float4 s = {0.f, 0.f, 0.f, 0.f};
    for (int g = 0; g < nseg; ++g) {
        float4 v = src[(size_t)g * stride4 + i4];
        s.x += v.x; s.y += v.y; s.z += v.z; s.w += v.w;
    }
    int c0 = (i4 & 7) * 4;
    float4 b4 = *(const float4*)(bias + c0);
    s.x += b4.x; s.y += b4.y; s.z += b4.z; s.w += b4.w;
    if (c0 < 16) {
        s.x = fmaxf(s.x, 0.f); s.y = fmaxf(s.y, 0.f);
        s.z = fmaxf(s.z, 0.f); s.w = fmaxf(s.w, 0.f);
    }
    dst[i4] = s;
    float4 s2 = {s.x * s.x, s.y * s.y, s.z * s.z, s.w * s.w};
    #pragma unroll
    for (int mask = 8; mask <= 32; mask <<= 1) {
        s.x += __shfl_xor(s.x, mask); s.y += __shfl_xor(s.y, mask);
        s.z += __shfl_xor(s.z, mask); s.w += __shfl_xor(s.w, mask);
        s2.x += __shfl_xor(s2.x, mask); s2.y += __shfl_xor(s2.y, mask);
        s2.z += __shfl_xor(s2.z, mask); s2.w += __shfl_xor(s2.w, mask);
    }
    int w = tid >> 6, ln = tid & 63;
    if (ln < 8) {
        lsum[w][ln][0] = s.x;  lsum[w][ln][1] = s.y;  lsum[w][ln][2] = s.z;  lsum[w][ln][3] = s.w;
        lsum[w][ln][4] = s2.x; lsum[w][ln][5] = s2.y; lsum[w][ln][6] = s2.z; lsum[w][ln][7] = s2.w;
    }
    __syncthreads();
    if (tid < 64) {
        int q = tid >> 3, e = tid & 7;
        float v = lsum[0][q][e] + lsum[1][q][e] + lsum[2][q][e] + lsum[3][q][e];
        int col = q * 4 + (e & 3);
        atomAddF((e < 4) ? &st[col] : &st[32 + col], v);
    }
}

// ---------------- final: sum x-partials + bl -> out ----------------
__global__ __launch_bounds__(256) void out_final(const float* __restrict__ px,
                                                 const float* __restrict__ bl,
                                                 float* __restrict__ out) {
    int tid = blockIdx.x * 256 + threadIdx.x;
    if (tid < 4096) {
        int n = tid >> 1, c = tid & 1;
        float a = bl[c];
        for (int s = 0; s < 14; ++s) a += px[(size_t)s * 65536 + n * 32 + c];
        out[tid] = a;
    }
}

extern "C" void kernel_launch(void* const* d_in, const int* in_sizes, int n_in,
                              void* d_out, int out_size, void* d_ws, size_t ws_size,
                              hipStream_t stream) {
    const float* W    = (const float*)d_in[0];
    const float* x    = (const float*)d_in[1];
    const float* WL   = (const float*)d_in[2];
    const float* y    = (const float*)d_in[3];
    const float* P    = (const float*)d_in[4];
    const float* wx2x0 = (const float*)d_in[5];
    const float* wy2x0 = (const float*)d_in[6];
    const float* bx0   = (const float*)d_in[7];
    const float* wy2y0 = (const float*)d_in[8];
    const float* wx2y0 = (const float*)d_in[9];
    const float* by0   = (const float*)d_in[10];
    const float* gx0   = (const float*)d_in[11];
    const float* btx0  = (const float*)d_in[12];
    const float* gy0   = (const float*)d_in[13];
    const float* bty0  = (const float*)d_in[14];
    const float* wx2x_m = (const float*)d_in[15];
    const float* wy2x_m = (const float*)d_in[16];
    const float* bx_m   = (const float*)d_in[17];
    const float* wy2y_m = (const float*)d_in[18];
    const float* wx2y_m = (const float*)d_in[19];
    const float* by_m   = (const float*)d_in[20];
    const float* gx_m   = (const float*)d_in[21];
    const float* btx_m  = (const float*)d_in[22];
    const float* gy_m   = (const float*)d_in[23];
    const float* bty_m  = (const float*)d_in[24];
    const float* wlx = (const float*)d_in[25];
    const float* wly = (const float*)d_in[26];
    const float* bl  = (const float*)d_in[27];

    char* base = (char*)d_ws;
    unsigned short* Wb  = (unsigned short*)(base + 0);          // 25,165,824 B
    unsigned short* Pb  = (unsigned short*)(base + 25165824);   // 33,554,432 B
    unsigned short* WLb = (unsigned short*)(base + 58720256);   // 100,663,296 B
    unsigned short* PTb = (unsigned short*)(base + 159383552);  // 33,554,432 B
    unsigned short* B1f = (unsigned short*)(base + 192937984);  // 917,504 B
    unsigned short* B2f = (unsigned short*)(base + 193855488);  // 1,048,576 B
    float* zax   = (float*)(base + 194904064);  // 262,144 B
    float* zay   = (float*)(base + 195166208);  // 524,288 B
    float* stats = (float*)(base + 195690496);  // 512 B
    float* px    = (float*)(base + 195691008);  // 14*65536*4  = 3,670,016 B
    float* py    = (float*)(base + 199361024);  // 16*131072*4 = 8,388,608 B

    // one-time conversions into packed layout
    cvt_pack<<<38912, 256, 0, stream>>>(W, P, WL, Wb, Pb, WLb);
    transpose_p<<<4096, 256, 0, stream>>>(P, PTb);

    // block 0 (Fin = 1, raw x/y, no bn)
    build_b<<<3840, 256, 0, stream>>>(x, y, 1, 32, 1, 0, nullptr, nullptr, nullptr, nullptr, nullptr,
                                      wx2x0, wy2x0, wy2y0, wx2y0, B1f, B2f);
    gemm_k<<<2944, 256, 0, stream>>>(Wb, Pb, WLb, PTb, B1f, B2f, px, py, stats, 896);
    reduce_stats<<<192, 256, 0, stream>>>(px, py, bx0, by0, zax, zay, stats);

    // blocks 1..6 (middle weights i = 0..5); bn params of block i come from previous block
    for (int i = 0; i < 6; ++i) {
        const float* gv  = (i == 0) ? gx0  : gx_m  + (i - 1) * 32;
        const float* bv  = (i == 0) ? btx0 : btx_m + (i - 1) * 32;
        const float* gvy = (i == 0) ? gy0  : gy_m  + (i - 1) * 32;
        const float* bvy = (i == 0) ? bty0 : bty_m + (i - 1) * 32;
        build_b<<<3840, 256, 0, stream>>>(zax, zay, 32, 32, 1, 1, stats, gv, bv, gvy, bvy,
                                          wx2x_m + i * 3072, wy2x_m + i * 2048,
                                          wy2y_m + i * 3072, wx2y_m + i * 2048, B1f, B2f);
        gemm_k<<<2944, 256, 0, stream>>>(Wb, Pb, WLb, PTb, B1f, B2f, px, py, stats, 896);
        reduce_stats<<<192, 256, 0, stream>>>(px, py, bx_m + i * 32, by_m + i * 32, zax, zay, stats);
    }

    // final layer: bn of block 6 (gx_m[5]...), linear weights, x-branch only
    build_b<<<1792, 256, 0, stream>>>(zax, zay, 32, 2, 0, 1, stats,
                                      gx_m + 5 * 32, btx_m + 5 * 32, gy_m + 5 * 32, bty_m + 5 * 32,
                                      wlx, wly, nullptr, nullptr, B1f, B2f);
    gemm_k<<<896, 256, 0, stream>>>(Wb, Pb, WLb, PTb, B1f, B2f, px, py, stats, 896);
    out_final<<<16, 256, 0, stream>>>(px, bl, (float*)d_out);
}

// Round 9
// 679.735 us; speedup vs baseline: 1.0657x; 1.0050x over previous
//
#include <hip/hip_runtime.h>

typedef _Float16 f16x8 __attribute__((ext_vector_type(8)));
typedef float f32x4 __attribute__((ext_vector_type(4)));

// Packed ("fragment-major") A layout: half-index of element (row,k), row-length K:
//   off = (row>>4)*(K*16) + (k>>5)*512 + ((((k>>3)&3)*16 + (row&15))*8) + (k&7)
// A wave reading lane*8..lane*8+7 at one kstep gets a contiguous 1KB block ==
// its MFMA A-fragment (row = lane&15, k = kstep*32 + (lane>>4)*8 + e).

__device__ inline unsigned short f16b(float v) {
    _Float16 h = (_Float16)v;
    return __builtin_bit_cast(unsigned short, h);
}

__device__ inline void atomAddF(float* p, float v) {
    __hip_atomic_fetch_add(p, v, __ATOMIC_RELAXED, __HIP_MEMORY_SCOPE_AGENT);
}

// ---------------- one-time fp32 -> packed fp16 (W, WL only; P handled in transpose) ----------------
template<int K>
__device__ inline void pack_cvt(const float* __restrict__ src, unsigned short* __restrict__ dst, int u) {
    int o = u * 8;
    int panel = o / (K * 16);
    int rem = o - panel * (K * 16);
    int kstep = rem >> 9;
    int rem2 = rem & 511;
    int g = rem2 >> 7;
    int r15 = (rem2 >> 3) & 15;
    int row = (panel << 4) | r15;
    int k = (kstep << 5) | (g << 3);
    const float4* s = (const float4*)(src + (size_t)row * K + k);
    float4 v0 = s[0], v1 = s[1];
    uint4 q;
    q.x = (unsigned)f16b(v0.x) | ((unsigned)f16b(v0.y) << 16);
    q.y = (unsigned)f16b(v0.z) | ((unsigned)f16b(v0.w) << 16);
    q.z = (unsigned)f16b(v1.x) | ((unsigned)f16b(v1.y) << 16);
    q.w = (unsigned)f16b(v1.z) | ((unsigned)f16b(v1.w) << 16);
    ((uint4*)dst)[u] = q;
}

// 16B-units: W 1572864, WL 6291456; grid-stride over 2048 blocks (15 iters/thread)
__global__ __launch_bounds__(256) void cvt_pack(const float* __restrict__ W, const float* __restrict__ WL,
                                                unsigned short* __restrict__ Wb, unsigned short* __restrict__ WLb) {
    const int NW = 1572864, TOT = 1572864 + 6291456;
    for (int u = blockIdx.x * 256 + threadIdx.x; u < TOT; u += 2048 * 256) {
        if (u < NW) pack_cvt<6144>(W, Wb, u);
        else pack_cvt<12288>(WL, WLb, u - NW);
    }
}

// P [2048][4096][2] f32 -> packed PT (row m, K=4096, PT[m][n*2+p]) AND packed Pb (row n, K=8192, Pb[n][m*2+p])
__global__ __launch_bounds__(256) void transpose_p(const float* __restrict__ P,
                                                   unsigned short* __restrict__ Pb,
                                                   unsigned short* __restrict__ PT) {
    __shared__ unsigned int lds[64][33];
    int bid = blockIdx.x;
    int m0 = (bid & 127) * 32;
    int n0 = (bid >> 7) * 64;
    int tid = threadIdx.x;
    const float2* P2 = (const float2*)P;
    #pragma unroll
    for (int it = 0; it < 8; ++it) {
        int idx = it * 256 + tid;
        int nl = idx >> 5, ml = idx & 31;
        float2 v = P2[(size_t)(n0 + nl) * 4096 + (m0 + ml)];
        unsigned int pk = (unsigned int)f16b(v.x) | ((unsigned int)f16b(v.y) << 16);
        lds[nl][ml] = pk;
    }
    __syncthreads();
    // y-branch PT: row = m, k = n*2+p  (K=4096, panel stride 65536 halves)
    unsigned int* PTu = (unsigned int*)PT;
    #pragma unroll
    for (int it = 0; it < 8; ++it) {
        int idx = it * 256 + tid;
        int ml = idx >> 6, nl = idx & 63;
        int row = m0 + ml;
        int k2 = (n0 + nl) * 2;
        int o = ((row >> 4) << 16) | ((k2 >> 5) << 9) | (((((k2 >> 3) & 3) << 4) | (row & 15)) << 3) | (k2 & 7);
        PTu[o >> 1] = lds[nl][ml];
    }
    // x-branch Pb: row = n, k = m*2+p  (K=8192, panel stride 131072 halves)
    unsigned int* Pbu = (unsigned int*)Pb;
    #pragma unroll
    for (int it = 0; it < 8; ++it) {
        int idx = it * 256 + tid;
        int nl = idx >> 5, ml = idx & 31;
        int row = n0 + nl;
        int k = (m0 + ml) * 2;
        int o = (row >> 4) * 131072 + ((k >> 5) << 9) + (((((k >> 3) & 3) << 4) | (row & 15)) << 3) + (k & 7);
        Pbu[o >> 1] = lds[nl][ml];
    }
}

// ---------------- per-layer B-matrix build (fragment layout), pure fma via sc/sh ----------------
// stats layout (floats): [0..63] x sums (sum,sumsq), [64..127] y sums, [128] counter,
//                        [132..163] scx, [164..195] shx, [196..227] scy, [228..259] shy
__global__ __launch_bounds__(256) void build_b(
    const float* __restrict__ srcx, const float* __restrict__ srcy,
    int Fin, int Fout, int buildB2, int use_bn,
    const float* __restrict__ stats,
    const float* __restrict__ w1a, const float* __restrict__ w1b,
    const float* __restrict__ w2a, const float* __restrict__ w2b,
    unsigned short* __restrict__ B1f, unsigned short* __restrict__ B2f) {
    int tid0 = blockIdx.x * 256 + threadIdx.x;
    const int NB1 = 14336 * 32;
    int isB2 = 0, t2 = tid0;
    if (tid0 >= NB1) {
        if (!buildB2) return;
        isB2 = 1; t2 = tid0 - NB1;
        if (t2 >= 16384 * 32) return;
    }
    int e = t2 & 7, lane = (t2 >> 3) & 63, hh = (t2 >> 9) & 1, t = t2 >> 10;
    int k = (t << 5) | ((lane >> 4) << 3) | e;
    int g = (hh << 4) | (lane & 15);
    float v = 0.f;
    if (g < Fout) {
        const float* hr; const float* wc; int useY;
        if (!isB2) {
            if (k < 6144) { int m = k / 3, j = k - 3 * m; hr = srcx + m * Fin; wc = w1a + (j * Fin) * Fout + g; useY = 0; }
            else { int k2 = k - 6144; int m = k2 >> 1, p = k2 & 1; hr = srcy + m * Fin; wc = w1b + (p * Fin) * Fout + g; useY = 1; }
        } else {
            if (k < 12288) { int m = k / 3, j = k - 3 * m; hr = srcy + m * Fin; wc = w2a + (j * Fin) * Fout + g; useY = 1; }
            else { int k2 = k - 12288; int n = k2 >> 1, p = k2 & 1; hr = srcx + n * Fin; wc = w2b + (p * Fin) * Fout + g; useY = 0; }
        }
        float a = 0.f;
        if (use_bn) {
            const float* sc = useY ? stats + 196 : stats + 132;
            const float* sh = useY ? stats + 228 : stats + 164;
            #pragma unroll
            for (int f = 0; f < 32; ++f) {
                float h = sc[f] * hr[f] + sh[f];
                a += h * wc[f * Fout];
            }
        } else {
            for (int f = 0; f < Fin; ++f) a += hr[f] * wc[f * Fout];
        }
        v = a;
    }
    if (!isB2) B1f[t2] = f16b(v); else B2f[t2] = f16b(v);
}

// ---------------- split-K MFMA GEMM over packed A, 4-wave k-split per tile ----------------
// x-branch: 64 mwgs x 14 ksegs = 896 WGs (segs 0..5 = W, 6..13 = P)
// y-branch: 128 mwgs x 16 ksegs = 2048 WGs (segs 0..11 = WL, 12..15 = PT)
__global__ __launch_bounds__(256) void gemm_k(
    const unsigned short* __restrict__ Wb, const unsigned short* __restrict__ Pb,
    const unsigned short* __restrict__ WLb, const unsigned short* __restrict__ PTb,
    const unsigned short* __restrict__ B1f, const unsigned short* __restrict__ B2f,
    float* __restrict__ px, float* __restrict__ py, float* __restrict__ stats, int nwgx) {
    __shared__ float lds[4][1024];
    int bid = blockIdx.x;
    if (bid == 0 && threadIdx.x < 132) stats[threadIdx.x] = 0.f;  // zero sums + counter for next reduce
    const unsigned short* Bf;
    float* Z;
    int seg, Mbase, K, kloc, kb;
    const unsigned short* A16;
    if (bid < nwgx) {
        Bf = B1f;
        int mwg = bid / 14; seg = bid % 14;
        Mbase = mwg * 32;
        kb = seg << 10;
        Z = px + (size_t)seg * 65536;
        if (seg < 6) { K = 6144; kloc = kb;        A16 = Wb; }
        else         { K = 8192; kloc = kb - 6144; A16 = Pb; }
    } else {
        int b2 = bid - nwgx;
        Bf = B2f;
        int mwg = b2 / 16; seg = b2 % 16;
        Mbase = mwg * 32;
        kb = seg << 10;
        Z = py + (size_t)seg * 131072;
        if (seg < 12) { K = 12288; kloc = kb;         A16 = WLb; }
        else          { K = 4096;  kloc = kb - 12288; A16 = PTb; }
    }
    int wid = threadIdx.x >> 6, lane = threadIdx.x & 63;
    int kq = wid << 8;  // this wave's 256-K quarter
    const unsigned short* ap0 = A16 + (size_t)(Mbase >> 4) * (K * 16)
                              + (size_t)((kloc + kq) >> 5) * 512 + lane * 8;
    const unsigned short* ap1 = ap0 + (size_t)K * 16;  // next 16-row panel
    const unsigned short* bp = Bf + ((size_t)((kb + kq) >> 5)) * 1024 + lane * 8;
    f32x4 acc00 = {0.f,0.f,0.f,0.f}, acc01 = {0.f,0.f,0.f,0.f};
    f32x4 acc10 = {0.f,0.f,0.f,0.f}, acc11 = {0.f,0.f,0.f,0.f};
    #pragma unroll
    for (int ks = 0; ks < 8; ++ks) {
        f16x8 a0 = *(const f16x8*)ap0;
        f16x8 a1 = *(const f16x8*)ap1;
        f16x8 b0 = *(const f16x8*)bp;
        f16x8 b1 = *(const f16x8*)(bp + 512);
        acc00 = __builtin_amdgcn_mfma_f32_16x16x32_f16(a0, b0, acc00, 0, 0, 0);
        acc10 = __builtin_amdgcn_mfma_f32_16x16x32_f16(a1, b0, acc10, 0, 0, 0);
        acc01 = __builtin_amdgcn_mfma_f32_16x16x32_f16(a0, b1, acc01, 0, 0, 0);
        acc11 = __builtin_amdgcn_mfma_f32_16x16x32_f16(a1, b1, acc11, 0, 0, 0);
        ap0 += 512; ap1 += 512; bp += 1024;
    }
    int col = lane & 15, r0 = (lane >> 4) << 2;
    float* l = lds[wid];
    #pragma unroll
    for (int r = 0; r < 4; ++r) {
        l[(r0 + r) * 32 + col]            = acc00[r];
        l[(r0 + r) * 32 + col + 16]       = acc01[r];
        l[(r0 + r + 16) * 32 + col]       = acc10[r];
        l[(r0 + r + 16) * 32 + col + 16]  = acc11[r];
    }
    __syncthreads();
    int t = threadIdx.x;
    float4 a = ((const float4*)lds[0])[t];
    float4 b = ((const float4*)lds[1])[t];
    float4 c = ((const float4*)lds[2])[t];
    float4 d = ((const float4*)lds[3])[t];
    float4 s;
    s.x = (a.x + b.x) + (c.x + d.x);
    s.y = (a.y + b.y) + (c.y + d.y);
    s.z = (a.z + b.z) + (c.z + d.z);
    s.w = (a.w + b.w) + (c.w + d.w);
    ((float4*)(Z + (size_t)Mbase * 32))[t] = s;
}

// ---------------- reduce partials + bias + relu-half + column stats + BN finalize ----------------
// blocks 0..63: x, 64..191: y; last finishing block converts sums -> scale/shift
__global__ __launch_bounds__(256) void reduce_stats(
    const float* __restrict__ px, const float* __restrict__ py,
    const float* __restrict__ bx, const float* __restrict__ by,
    const float* __restrict__ gx, const float* __restrict__ btx,
    const float* __restrict__ gy, const float* __restrict__ bty,
    float* __restrict__ zax, float* __restrict__ zay,
    float* __restrict__ stats) {
    __shared__ float lsum[4][8][8];
    __shared__ int lastFlag;
    int bid = blockIdx.x, tid = threadIdx.x;
    const float4* src; const float* bias; float4* dst; float* st; int nseg, i4, stride4;
    if (bid < 64) { src = (const float4*)px; bias = bx; dst = (float4*)zax; st = stats;      nseg = 14; i4 = bid * 256 + tid;        stride4 = 16384; }
    else          { src = (const float4*)py; bias = by; dst = (float4*)zay; st = stats + 64; nseg = 16; i4 = (bid - 64) * 256 + tid; stride4 = 32768; }
    float4 s = {0.f, 0.f, 0.f, 0.f};
    for (int g = 0; g < nseg; ++g) {
        float4 v = src[(size_t)g * stride4 + i4];
        s.x += v.x; s.y += v.y; s.z += v.z; s.w += v.w;
    }
    int c0 = (i4 & 7) * 4;
    float4 b4 = *(const float4*)(bias + c0);
    s.x += b4.x; s.y += b4.y; s.z += b4.z; s.w += b4.w;
    if (c0 < 16) {
        s.x = fmaxf(s.x, 0.f); s.y = fmaxf(s.y, 0.f);
        s.z = fmaxf(s.z, 0.f); s.w = fmaxf(s.w, 0.f);
    }
    dst[i4] = s;
    float4 s2 = {s.x * s.x, s.y * s.y, s.z * s.z, s.w * s.w};
    #pragma unroll
    for (int mask = 8; mask <= 32; mask <<= 1) {
        s.x += __shfl_xor(s.x, mask); s.y += __shfl_xor(s.y, mask);
        s.z += __shfl_xor(s.z, mask); s.w += __shfl_xor(s.w, mask);
        s2.x += __shfl_xor(s2.x, mask); s2.y += __shfl_xor(s2.y, mask);
        s2.z += __shfl_xor(s2.z, mask); s2.w += __shfl_xor(s2.w, mask);
    }
    int w = tid >> 6, ln = tid & 63;
    if (ln < 8) {
        lsum[w][ln][0] = s.x;  lsum[w][ln][1] = s.y;  lsum[w][ln][2] = s.z;  lsum[w][ln][3] = s.w;
        lsum[w][ln][4] = s2.x; lsum[w][ln][5] = s2.y; lsum[w][ln][6] = s2.z; lsum[w][ln][7] = s2.w;
    }
    __syncthreads();
    if (tid < 64) {
        int q = tid >> 3, e = tid & 7;
        float v = lsum[0][q][e] + lsum[1][q][e] + lsum[2][q][e] + lsum[3][q][e];
        int col = q * 4 + (e & 3);
        atomAddF((e < 4) ? &st[col] : &st[32 + col], v);
    }
    __syncthreads();
    if (tid == 0) {
        __threadfence();
        int old = __hip_atomic_fetch_add((int*)(stats + 128), 1, __ATOMIC_ACQ_REL, __HIP_MEMORY_SCOPE_AGENT);
        lastFlag = (old == 191) ? 1 : 0;
    }
    __syncthreads();
    if (lastFlag && tid < 64) {
        int f = tid & 31, isY = tid >> 5;
        float* sb = stats + (isY ? 64 : 0);
        float n = isY ? 4096.f : 2048.f;
        float sum = __hip_atomic_load(&sb[f], __ATOMIC_RELAXED, __HIP_MEMORY_SCOPE_AGENT);
        float ssq = __hip_atomic_load(&sb[32 + f], __ATOMIC_RELAXED, __HIP_MEMORY_SCOPE_AGENT);
        float mean = sum / n;
        float var = ssq / n - mean * mean;
        const float* gv = isY ? gy : gx;
        const float* bv = isY ? bty : btx;
        float sc = gv[f] * rsqrtf(var + 1e-5f);
        stats[132 + isY * 64 + f] = sc;
        stats[164 + isY * 64 + f] = bv[f] - mean * sc;
    }
}

// ---------------- final: sum x-partials + bl -> out ----------------
__global__ __launch_bounds__(256) void out_final(const float* __restrict__ px,
                                                 const float* __restrict__ bl,
                                                 float* __restrict__ out) {
    int tid = blockIdx.x * 256 + threadIdx.x;
    if (tid < 4096) {
        int n = tid >> 1, c = tid & 1;
        float a = bl[c];
        for (int s = 0; s < 14; ++s) a += px[(size_t)s * 65536 + n * 32 + c];
        out[tid] = a;
    }
}

extern "C" void kernel_launch(void* const* d_in, const int* in_sizes, int n_in,
                              void* d_out, int out_size, void* d_ws, size_t ws_size,
                              hipStream_t stream) {
    const float* W    = (const float*)d_in[0];
    const float* x    = (const float*)d_in[1];
    const float* WL   = (const float*)d_in[2];
    const float* y    = (const float*)d_in[3];
    const float* P    = (const float*)d_in[4];
    const float* wx2x0 = (const float*)d_in[5];
    const float* wy2x0 = (const float*)d_in[6];
    const float* bx0   = (const float*)d_in[7];
    const float* wy2y0 = (const float*)d_in[8];
    const float* wx2y0 = (const float*)d_in[9];
    const float* by0   = (const float*)d_in[10];
    const float* gx0   = (const float*)d_in[11];
    const float* btx0  = (const float*)d_in[12];
    const float* gy0   = (const float*)d_in[13];
    const float* bty0  = (const float*)d_in[14];
    const float* wx2x_m = (const float*)d_in[15];
    const float* wy2x_m = (const float*)d_in[16];
    const float* bx_m   = (const float*)d_in[17];
    const float* wy2y_m = (const float*)d_in[18];
    const float* wx2y_m = (const float*)d_in[19];
    const float* by_m   = (const float*)d_in[20];
    const float* gx_m   = (const float*)d_in[21];
    const float* btx_m  = (const float*)d_in[22];
    const float* gy_m   = (const float*)d_in[23];
    const float* bty_m  = (const float*)d_in[24];
    const float* wlx = (const float*)d_in[25];
    const float* wly = (const float*)d_in[26];
    const float* bl  = (const float*)d_in[27];

    char* base = (char*)d_ws;
    unsigned short* Wb  = (unsigned short*)(base + 0);          // 25,165,824 B
    unsigned short* Pb  = (unsigned short*)(base + 25165824);   // 33,554,432 B
    unsigned short* WLb = (unsigned short*)(base + 58720256);   // 100,663,296 B
    unsigned short* PTb = (unsigned short*)(base + 159383552);  // 33,554,432 B
    unsigned short* B1f = (unsigned short*)(base + 192937984);  // 917,504 B
    unsigned short* B2f = (unsigned short*)(base + 193855488);  // 1,048,576 B
    float* zax   = (float*)(base + 194904064);  // 262,144 B
    float* zay   = (float*)(base + 195166208);  // 524,288 B
    float* stats = (float*)(base + 195690496);  // 2,048 B (sums, counter, sc/sh)
    float* px    = (float*)(base + 195692544);  // 14*65536*4  = 3,670,016 B
    float* py    = (float*)(base + 199362560);  // 16*131072*4 = 8,388,608 B -> ends 207,751,168

    // one-time conversions into packed layout (P read once, in transpose)
    cvt_pack<<<2048, 256, 0, stream>>>(W, WL, Wb, WLb);
    transpose_p<<<4096, 256, 0, stream>>>(P, Pb, PTb);

    // block 0 (Fin = 1, raw x/y, no bn)
    build_b<<<3840, 256, 0, stream>>>(x, y, 1, 32, 1, 0, stats,
                                      wx2x0, wy2x0, wy2y0, wx2y0, B1f, B2f);
    gemm_k<<<2944, 256, 0, stream>>>(Wb, Pb, WLb, PTb, B1f, B2f, px, py, stats, 896);
    reduce_stats<<<192, 256, 0, stream>>>(px, py, bx0, by0, gx0, btx0, gy0, bty0, zax, zay, stats);

    // blocks 1..6 (middle weights i = 0..5); reduce_i finalizes BN of block i
    for (int i = 0; i < 6; ++i) {
        build_b<<<3840, 256, 0, stream>>>(zax, zay, 32, 32, 1, 1, stats,
                                          wx2x_m + i * 3072, wy2x_m + i * 2048,
                                          wy2y_m + i * 3072, wx2y_m + i * 2048, B1f, B2f);
        gemm_k<<<2944, 256, 0, stream>>>(Wb, Pb, WLb, PTb, B1f, B2f, px, py, stats, 896);
        reduce_stats<<<192, 256, 0, stream>>>(px, py, bx_m + i * 32, by_m + i * 32,
                                              gx_m + i * 32, btx_m + i * 32,
                                              gy_m + i * 32, bty_m + i * 32, zax, zay, stats);
    }

    // final layer: consumes BN of block 6 (finalized by loop i=5 reduce), linear weights, x-branch only
    build_b<<<1792, 256, 0, stream>>>(zax, zay, 32, 2, 0, 1, stats,
                                      wlx, wly, nullptr, nullptr, B1f, B2f);
    gemm_k<<<896, 256, 0, stream>>>(Wb, Pb, WLb, PTb, B1f, B2f, px, py, stats, 896);
    out_final<<<16, 256, 0, stream>>>(px, bl, (float*)d_out);
}